// Round 3
// baseline (666.806 us; speedup 1.0000x reference)
//
#include <hip/hip_runtime.h>

#define LOG2E 1.44269504088896340736f

// Broadcast lane `lane`'s value to all lanes (wave-uniform SGPR result).
__device__ __forceinline__ float rl(float v, int lane) {
    return __int_as_float(__builtin_amdgcn_readlane(__float_as_int(v), lane));
}

// One wave per sequence. Lane l owns gate rows r0=l (i/f) and r1=l+64 (g/o).
// Round-2 lesson: the register allocator refuses to keep 64 weights in arch
// VGPRs (VGPR_Count=68 -> AGPR copies, ~128 extra VALU cyc/step). So W_hh
// lives in LDS and is re-read every step on the DS pipe (parallel to VALU):
// 16 ds_read_b128/step, issued dependency-free at step top. h is broadcast
// through LDS (1 write + 6 broadcast b128 reads) with a readlane head-start
// for k=0..7 to cover the write->read latency. Weights/biases are pre-scaled
// by -log2e (sigmoid rows) / -2log2e (tanh rows) so each activation is just
// exp2 + add + rcp.
__global__ __launch_bounds__(64, 1) void lstm_seq_kernel(
    const float* __restrict__ x,      // [B, T]
    const float* __restrict__ W_ih,   // [128]
    const float* __restrict__ W_hh,   // [128, 32]
    const float* __restrict__ b_ih,   // [128]
    const float* __restrict__ b_hh,   // [128]
    const float* __restrict__ W_out,  // [32]
    const float* __restrict__ b_out,  // [1]
    float* __restrict__ out,          // [B, T]
    int T)
{
    __shared__ float wsh[128 * 36];   // rows padded to 36 floats: 16B-aligned,
                                      // b128 reads spread uniformly over banks
    __shared__ float psum[64 * 68];   // per-step output partials (round-2 scheme)
    __shared__ float hbuf[64];        // h broadcast buffer
    __shared__ float xbuf[64];        // staged x chunk

    const int b = blockIdx.x;
    const int l = threadIdx.x;        // 0..63
    const int r0 = l;                 // i (l<32) / f (l>=32): sigmoid rows
    const int r1 = l + 64;           // g (l<32) / o (l>=32)
    const bool lo = (l < 32);

    const float sc0 = -LOG2E;                          // sigmoid prescale
    const float sc1 = lo ? (-2.0f * LOG2E) : (-LOG2E); // tanh / sigmoid prescale

    // One-time: stage prescaled W_hh rows into LDS.
#pragma unroll
    for (int m = 0; m < 8; ++m) {
        float4 a = *(const float4*)(W_hh + r0 * 32 + 4 * m);
        a.x *= sc0; a.y *= sc0; a.z *= sc0; a.w *= sc0;
        *(float4*)(wsh + r0 * 36 + 4 * m) = a;
        float4 g = *(const float4*)(W_hh + r1 * 32 + 4 * m);
        g.x *= sc1; g.y *= sc1; g.z *= sc1; g.w *= sc1;
        *(float4*)(wsh + r1 * 36 + 4 * m) = g;
    }

    const float wih0  = W_ih[r0] * sc0;
    const float wih1  = W_ih[r1] * sc1;
    const float bias0 = (b_ih[r0] + b_hh[r0]) * sc0;
    const float bias1 = (b_ih[r1] + b_hh[r1]) * sc1;
    const float A1 = lo ? 2.0f : 1.0f;   // tanh = 2*rcp(..)-1 ; sigmoid = rcp(..)
    const float B1 = lo ? -1.0f : 0.0f;
    const float woutv = lo ? W_out[l] : 0.0f;  // upper half duplicates h -> 0
    const float bout  = b_out[0];

    float h = 0.0f, c = 0.0f;
    hbuf[l] = 0.0f;

    const float* xp = x + (size_t)b * T;
    float*       op = out + (size_t)b * T;
    float xv = xp[l];

    __syncthreads();

    for (int t0 = 0; t0 < T; t0 += 64) {
        xbuf[l] = xv;
        const int tn = (t0 + 64 < T) ? (t0 + 64) : t0;
        float xv_next = xp[tn + l];   // prefetch next chunk (hidden)
        asm volatile("" ::: "memory");

#pragma unroll 8
        for (int tu = 0; tu < 64; ++tu) {
            // Step-top LDS reads (DS pipe, overlap with VALU chain below).
            float wreg0[32], wreg1[32], hreg[32];
            const float4* w0p = (const float4*)(wsh + r0 * 36);
            const float4* w1p = (const float4*)(wsh + r1 * 36);
            const float4* hb  = (const float4*)hbuf;
#pragma unroll
            for (int m = 2; m < 8; ++m)           // h[8..31] via LDS broadcast
                *(float4*)&hreg[4 * m] = hb[m];
#pragma unroll
            for (int m = 0; m < 8; ++m) {         // this lane's two weight rows
                *(float4*)&wreg0[4 * m] = w0p[m];
                *(float4*)&wreg1[4 * m] = w1p[m];
            }
            const float xt = xbuf[tu];            // uniform-address broadcast

            float a0 = fmaf(wih0, xt, bias0);
            float a1 = fmaf(wih1, xt, bias1);
            float b0 = 0.0f, b1 = 0.0f;
            // k=0..7 via readlane (starts immediately, covers LDS round-trip);
            // k=8..31 from the broadcast reads.
#pragma unroll
            for (int k = 0; k < 32; k += 2) {
                const float hk0 = (k     < 8) ? rl(h, k)     : hreg[k];
                const float hk1 = (k + 1 < 8) ? rl(h, k + 1) : hreg[k + 1];
                a0 = fmaf(wreg0[k],     hk0, a0);
                b0 = fmaf(wreg0[k + 1], hk1, b0);
                a1 = fmaf(wreg1[k],     hk0, a1);
                b1 = fmaf(wreg1[k + 1], hk1, b1);
            }
            const float G0 = a0 + b0;   // pre-scaled: -log2e * preact
            const float G1 = a1 + b1;

            const float s0 = __builtin_amdgcn_rcpf(
                1.0f + __builtin_amdgcn_exp2f(G0));           // sigmoid(i/f)
            const float s1 = fmaf(A1, __builtin_amdgcn_rcpf(
                1.0f + __builtin_amdgcn_exp2f(G1)), B1);      // tanh(g)/sigmoid(o)

            // Exchange across half-wave: (i,g) <-> (f,o)
            const float o0 = __shfl_xor(s0, 32, 64);
            const float o1 = __shfl_xor(s1, 32, 64);
            const float iv = lo ? s0 : o0;
            const float fv = lo ? o0 : s0;
            const float gv = lo ? s1 : o1;
            const float oV = lo ? o1 : s1;

            c = fmaf(fv, c, iv * gv);
            const float tc = fmaf(2.0f, __builtin_amdgcn_rcpf(
                1.0f + __builtin_amdgcn_exp2f(-2.0f * LOG2E * c)), -1.0f);
            h = oV * tc;

            hbuf[l] = h;                          // next step's broadcast source
            psum[tu * 68 + l] = h * woutv;        // fire-and-forget partial
            // Order write(t) before reads(t+1); also forces per-step LDS
            // re-read (defeats LICM re-hoisting weights into registers).
            asm volatile("" ::: "memory");
        }

        __syncthreads();  // single wave: cheap; drain psum writes
        // Lane j reduces psum row j -> out[t0+j].
        const float4* row = (const float4*)(psum + l * 68);
        float4 s4 = row[0];
#pragma unroll
        for (int m = 1; m < 16; ++m) {
            float4 v4 = row[m];
            s4.x += v4.x; s4.y += v4.y; s4.z += v4.z; s4.w += v4.w;
        }
        op[t0 + l] = (s4.x + s4.y) + (s4.z + s4.w) + bout;
        __syncthreads();
        xv = xv_next;
    }
}

extern "C" void kernel_launch(void* const* d_in, const int* in_sizes, int n_in,
                              void* d_out, int out_size, void* d_ws, size_t ws_size,
                              hipStream_t stream) {
    const float* x     = (const float*)d_in[0];   // [1024, 2048, 1]
    const float* W_ih  = (const float*)d_in[1];   // [128, 1]
    const float* W_hh  = (const float*)d_in[2];   // [128, 32]
    const float* b_ih  = (const float*)d_in[3];   // [128]
    const float* b_hh  = (const float*)d_in[4];   // [128]
    const float* W_out = (const float*)d_in[5];   // [1, 32]
    const float* b_out = (const float*)d_in[6];   // [1]
    float* out = (float*)d_out;                   // [1024, 2048, 1]

    const int B = 1024;
    const int T = 2048;
    lstm_seq_kernel<<<B, 64, 0, stream>>>(x, W_ih, W_hh, b_ih, b_hh,
                                          W_out, b_out, out, T);
}